// Round 15
// baseline (347.952 us; speedup 1.0000x reference)
//
#include <hip/hip_runtime.h>
#include <cstddef>

#define B_ROWS 8192
#define DIM    1024
#define NSESS  32
#define MT     192       // rows per M-tile; balanced split guarantees nrows<=192
#define NTILE  256       // cols per N-tile
#define BK     64        // fp32 per K-chunk per phase = 2 MFMA k-steps
#define KITERS (DIM / BK)   // 16
#define TPE    2         // m-tiles per expert (balanced halves)
#define LROW   72        // shorts per LDS row: 64 bf16 + 8 pad = 144 B (16B-mult)
#define TSZA   (MT * LROW)      // 13824 shorts = 27.6 KB
#define TSZB   (NTILE * LROW)   // 18432 shorts = 36.9 KB
#define NXCD   8
#define EPX    (NSESS / NXCD)        // experts per XCD = 4
#define BPE    (TPE * (DIM / NTILE)) // blocks per expert = 8

typedef __attribute__((ext_vector_type(8))) short short8;
typedef __attribute__((ext_vector_type(4))) float floatx4;
typedef __attribute__((ext_vector_type(4))) int intx4;
typedef __attribute__((ext_vector_type(2))) unsigned int uintx2;

// RNE fp32->bf16 for two values, packed into one dword via v_perm_b32.
__device__ __forceinline__ unsigned pack_bf16_2(float fa, float fb) {
  unsigned a = __builtin_bit_cast(unsigned, fa);
  unsigned b = __builtin_bit_cast(unsigned, fb);
  a += 0x7fffu + ((a >> 16) & 1u);
  b += 0x7fffu + ((b >> 16) & 1u);
  return __builtin_amdgcn_perm(b, a, 0x07060302u); // low = bf16(fa), high = bf16(fb)
}

// Round-20 (post-mortem r19: depth-3 gave +3% not +10% — because EVERY
// __syncthreads drains vmcnt to 0 (r14), so cross-barrier prefetch depth is
// fiction. What correlates across r13/r17/r19 is BYTES ISSUED PER PHASE:
// r13's BK=64 schedule (98KB/phase/block) ran at 10.4 B/cy/CU — the chip's
// m13 streaming ceiling (6.29TB/s/256CU/2.4GHz ~= 10.2); BK=32 variants
// (57-65KB/phase) run at ~8.3 (83%), paying 2x the per-phase latency
// exposures. This round combines the proven pieces:
//  - r13 BK=64 pair-loop VERBATIM (16 phases, 112KB issued/phase/block)
//  - r17 balanced split (nrows <= 192, all 256 blocks live, 1/CU)
//  - r18/r19 MT=192 acc diet (acc[6][4]=96) -> 2x56-reg load sets fit the
//    256/wave budget (r13 proved 236 live fits)
//  - NEW: A-loads predicated on row < nrows — typical nrows 105-155, so
//    37-87 of 192 staged A rows were dummy row-0 re-loads (~150-350 KB/block
//    waste). Garbage rows flow to LDS/MFMA, masked at epilogue (no traps).
//  - shfl wave-scan (2 barriers), r12 coalesced epilogue (6 passes max).
// Max-per-CU issued 1.77 -> ~1.62MB. LDS dbuf 129KB -> 1 block/CU (grid=1/CU
// anyway). Canaries: WRITE ~32.7MB + VGPR(arch) <= ~160 (tightest budget yet).
__global__ __launch_bounds__(512, 2) void gemm_kernel(
    const float* __restrict__ x, const float* __restrict__ W,
    const float* __restrict__ bias, const int* __restrict__ sidx,
    float* __restrict__ out)
{
  __shared__ __align__(16) short lds[2 * (TSZA + TSZB)]; // 129024 B flat
  __shared__ int row_ids[MT];
  __shared__ int wsum[8];
  short* const As0 = lds;
  short* const Bs0 = lds + TSZA;
  short* const As1 = lds + TSZA + TSZB;
  short* const Bs1 = lds + 2 * TSZA + TSZB;

  // ---- XCD-clustered decode ----
  const int hw    = blockIdx.x;          // 0..255, assumed XCD = hw % 8
  const int xcd   = hw & (NXCD - 1);
  const int r     = hw >> 3;             // 0..31: within-XCD sequence
  const int s     = xcd * EPX + (r / BPE);   // expert, clustered per XCD
  const int rr    = r % BPE;             // 0..7
  const int ntile = rr >> 1;             // 0..3 (W slice shared by 2 mtiles)
  const int mtile = rr & 1;
  const int tid   = threadIdx.x;

  const int lane = tid & 63;
  const int wv   = tid >> 6;            // wave id 0..7
  const int wm   = wv >> 2;             // 0..1 : 96-row half
  const int wn   = wv & 3;              // 0..3 : 64-col quarter
  const int fr   = lane & 15;           // fragment row within 16
  const int kg   = lane >> 4;           // fragment k-group (k = kg*8 + j)

  // ---- staging: row = 256 B fp32 = 16 x 16-B chunks; 512 thr -> 32 rows/instr
  const int srw = tid >> 4;             // 0..31 : row within 32-row group
  const int sch = tid & 15;             // 16-B chunk within 256-B k-row

  // B byte-offsets + k0/k1 B-loads issued before the sidx scan.
  unsigned boff[8];
  floatx4 wr0[8], wr1[8];
  {
    const unsigned wbyte =
        (unsigned)(((size_t)s * DIM * DIM + (size_t)(ntile * NTILE) * DIM) * 4u);
#pragma unroll
    for (int j = 0; j < 8; ++j) {
      const int tr = j * 32 + srw;
      boff[j] = wbyte + (unsigned)((tr * DIM + sch * 4) * 4);
      wr0[j] = *(const floatx4*)((const char*)W + boff[j]);
    }
#pragma unroll
    for (int j = 0; j < 8; ++j)
      wr1[j] = *(const floatx4*)((const char*)W + boff[j] + (BK * 4));
  }

  // ---- ranked compaction via shfl wave-scan (2 barriers total) ----
  const intx4* sv = (const intx4*)(sidx + tid * 16);
  int c = 0;
#pragma unroll
  for (int j = 0; j < 4; ++j) {
    const intx4 v = sv[j];
#pragma unroll
    for (int e = 0; e < 4; ++e) c += (v[e] == s);
  }
  int ic = c;                           // in-wave inclusive prefix
#pragma unroll
  for (int d = 1; d < 64; d <<= 1) {
    const int t = __shfl_up(ic, d);
    if (lane >= d) ic += t;
  }
  if (lane == 63) wsum[wv] = ic;
  __syncthreads();
  int wbase = 0, total = 0;
#pragma unroll
  for (int w = 0; w < 8; ++w) {
    const int v = wsum[w];
    total += v;
    if (w < wv) wbase += v;
  }
  // balanced split: mtile0 -> ranks [0,h), mtile1 -> [h,total); h=ceil(total/2)
  const int h     = (total + 1) >> 1;    // <= 192 for total <= 384 (validated)
  const int lo    = mtile * h;
  const int hi    = mtile ? total : h;
  const int nrows = hi - lo;
  if (nrows == 0) return;               // uniform across block
  const int base_rank = wbase + ic - c; // exclusive global prefix

  if (tid < MT) row_ids[tid] = -1;
  __syncthreads();
  {
    int r2 = base_rank;
#pragma unroll
    for (int j = 0; j < 4; ++j) {
      const intx4 v = sv[j];
#pragma unroll
      for (int e = 0; e < 4; ++e) {
        if (v[e] == s) {
          if (r2 >= lo && r2 < hi) row_ids[r2 - lo] = tid * 16 + 4 * j + e;
          ++r2;
        }
      }
    }
  }
  __syncthreads();

  // A byte-offsets; loads predicated on arow < nrows (dummy rows: garbage
  // registers -> garbage LDS rows -> masked at epilogue; no traps).
  unsigned aoff[6];
  floatx4 xr0[6], xr1[6];
#pragma unroll
  for (int j = 0; j < 6; ++j) {
    int ar = row_ids[j * 32 + srw];
    if (ar < 0) ar = 0;
    aoff[j] = (unsigned)((ar * DIM + sch * 4) * 4);
    if (j * 32 + srw < nrows)
      xr0[j] = *(const floatx4*)((const char*)x + aoff[j]);            // k0
  }
#pragma unroll
  for (int j = 0; j < 6; ++j)
    if (j * 32 + srw < nrows)
      xr1[j] = *(const floatx4*)((const char*)x + aoff[j] + (BK * 4)); // k1

  floatx4 acc[6][4] = {};

#define LOADSET(XR, WR, KB)                                                    \
  {                                                                            \
    _Pragma("unroll")                                                          \
    for (int j = 0; j < 6; ++j)                                                \
      if (j * 32 + srw < nrows)                                                \
        XR[j] = *(const floatx4*)((const char*)x + aoff[j] + (KB) * (BK * 4)); \
    _Pragma("unroll")                                                          \
    for (int j = 0; j < 8; ++j)                                                \
      WR[j] = *(const floatx4*)((const char*)W + boff[j] + (KB) * (BK * 4));   \
  }

#define CVTWRITE(XR, WR, AS, BS)                                               \
  {                                                                            \
    _Pragma("unroll")                                                          \
    for (int j = 0; j < 6; ++j) {                                              \
      const int off = (j * 32 + srw) * LROW + sch * 4;                         \
      uintx2 ua = { pack_bf16_2(XR[j][0], XR[j][1]),                           \
                    pack_bf16_2(XR[j][2], XR[j][3]) };                         \
      *(uintx2*)&AS[off] = ua;                                                 \
    }                                                                          \
    _Pragma("unroll")                                                          \
    for (int j = 0; j < 8; ++j) {                                              \
      const int off = (j * 32 + srw) * LROW + sch * 4;                         \
      uintx2 ub = { pack_bf16_2(WR[j][0], WR[j][1]),                           \
                    pack_bf16_2(WR[j][2], WR[j][3]) };                         \
      *(uintx2*)&BS[off] = ub;                                                 \
    }                                                                          \
  }

#define COMPUTE(AS, BS)                                                        \
  {                                                                            \
    _Pragma("unroll")                                                          \
    for (int s2 = 0; s2 < 2; ++s2) {                                           \
      short8 fb[4];                                                            \
      _Pragma("unroll")                                                        \
      for (int i = 0; i < 4; ++i)                                              \
        fb[i] = *(const short8*)&BS[(wn * 64 + i * 16 + fr) * LROW + s2 * 32 + kg * 8]; \
      _Pragma("unroll")                                                        \
      for (int mi = 0; mi < 6; ++mi) {                                         \
        const short8 fa = *(const short8*)&AS[(wm * 96 + mi * 16 + fr) * LROW + s2 * 32 + kg * 8]; \
        _Pragma("unroll")                                                      \
        for (int ni = 0; ni < 4; ++ni)                                         \
          acc[mi][ni] = __builtin_amdgcn_mfma_f32_16x16x32_bf16(               \
              fa, fb[ni], acc[mi][ni], 0, 0, 0);                               \
      }                                                                        \
    }                                                                          \
  }

  // prologue: k0 (set0) -> LDS0. set1 (k1) stays in flight.
  CVTWRITE(xr0, wr0, As0, Bs0);
  __syncthreads();

  // r13 pair loop: even chunks set0/LDS0, odd chunks set1/LDS1.
  for (int kb = 0; kb < KITERS; kb += 2) {
    if (kb + 2 < KITERS) LOADSET(xr0, wr0, kb + 2);
    COMPUTE(As0, Bs0);
    CVTWRITE(xr1, wr1, As1, Bs1);
    __syncthreads();

    if (kb + 3 < KITERS) LOADSET(xr1, wr1, kb + 3);
    COMPUTE(As1, Bs1);
    if (kb + 2 < KITERS) CVTWRITE(xr0, wr0, As0, Bs0);
    __syncthreads();
  }

#undef LOADSET
#undef CVTWRITE
#undef COMPUTE

  // ---- coalesced epilogue (r12; 192 rows -> up to 6 passes of 32) ---------
  // acc: tile row = wm*96 + mi*16 + kg*4 + q, col = wn*64 + ni*16 + fr.
  // Pass p: rows [32p,32p+32) via [32][260] f32 aliased onto lds (33280 B).
  // One dwordx4 store = 64 lanes x 16 B = FULL 1-KB output row. Early break
  // when the window is beyond nrows (block-uniform).
  float* obuf = (float*)lds;
  const int col0 = ntile * NTILE + wn * 64;
  float bv[4];
#pragma unroll
  for (int ni = 0; ni < 4; ++ni) bv[ni] = bias[s * DIM + col0 + ni * 16 + fr];

  const int rbase = tid >> 6;          // 0..7 : row within 8-row store group
  const int ch    = tid & 63;          // 16-B chunk within 1-KB row

#pragma unroll
  for (int p = 0; p < 6; ++p) {
    if (p * 32 >= nrows) break;        // block-uniform: no divergence
    if (wm == (p >= 3 ? 1 : 0)) {
#pragma unroll
      for (int mh = 0; mh < 2; ++mh) {
        const int mi = (p % 3) * 2 + mh;
        const int lr = mi * 16 + kg * 4 - (p % 3) * 32;   // 0..28 local row base
#pragma unroll
        for (int q = 0; q < 4; ++q)
#pragma unroll
          for (int ni = 0; ni < 4; ++ni)
            obuf[(lr + q) * 260 + wn * 64 + ni * 16 + fr] = acc[mi][ni][q] + bv[ni];
      }
    }
    __syncthreads();
#pragma unroll
    for (int j = 0; j < 4; ++j) {
      const int lr = j * 8 + rbase;              // 0..31
      const int ml = p * 32 + lr;                // tile row
      if (ml < nrows) {
        const int orow = row_ids[ml];
        const floatx4 v = *(const floatx4*)&obuf[lr * 260 + ch * 4];
        *(floatx4*)&out[(size_t)orow * DIM + ntile * NTILE + ch * 4] = v;
      }
    }
    __syncthreads();
  }
}

extern "C" void kernel_launch(void* const* d_in, const int* in_sizes, int n_in,
                              void* d_out, int out_size, void* d_ws, size_t ws_size,
                              hipStream_t stream) {
  const float* x    = (const float*)d_in[0];
  const float* W    = (const float*)d_in[1];
  const float* b    = (const float*)d_in[2];
  const int*   sidx = (const int*)d_in[3];
  float* out = (float*)d_out;
  (void)d_ws; (void)ws_size;  // OFF-LIMITS: any ws touch => 512MiB re-poison
                              // fill (~80us) per iteration (r9 post-mortem)

  hipLaunchKernelGGL(gemm_kernel, dim3(NSESS * TPE * (DIM / NTILE)), dim3(512),
                     0, stream, x, W, b, sidx, out);
}

// Round 16
// 280.893 us; speedup vs baseline: 1.2387x; 1.2387x over previous
//
#include <hip/hip_runtime.h>
#include <cstddef>

#define B_ROWS 8192
#define DIM    1024
#define NSESS  32
#define MT     192       // rows per M-tile; balanced split guarantees nrows<=192
#define NTILE  256       // cols per N-tile
#define BK     64        // fp32 per K-chunk per phase = 2 MFMA k-steps
#define KITERS (DIM / BK)   // 16
#define TPE    2         // m-tiles per expert (balanced halves)
#define LROW   72        // shorts per LDS row: 64 bf16 + 8 pad = 144 B (16B-mult)
#define TSZA   (MT * LROW)      // 13824 shorts = 27.6 KB
#define TSZB   (NTILE * LROW)   // 18432 shorts = 36.9 KB
#define NXCD   8
#define EPX    (NSESS / NXCD)        // experts per XCD = 4
#define BPE    (TPE * (DIM / NTILE)) // blocks per expert = 8

typedef __attribute__((ext_vector_type(8))) short short8;
typedef __attribute__((ext_vector_type(4))) float floatx4;
typedef __attribute__((ext_vector_type(4))) int intx4;
typedef __attribute__((ext_vector_type(2))) unsigned int uintx2;

// RNE fp32->bf16 for two values, packed into one dword via v_perm_b32.
__device__ __forceinline__ unsigned pack_bf16_2(float fa, float fb) {
  unsigned a = __builtin_bit_cast(unsigned, fa);
  unsigned b = __builtin_bit_cast(unsigned, fb);
  a += 0x7fffu + ((a >> 16) & 1u);
  b += 0x7fffu + ((b >> 16) & 1u);
  return __builtin_amdgcn_perm(b, a, 0x07060302u); // low = bf16(fa), high = bf16(fb)
}

// Round-21 (post-mortem r20: SPILL — WRITE 32.7->155MB. Derived law:
// held-bytes/thread = depth x 3.5 x BK -> {BK=64, depth-2} = 112 set-regs +
// acc 96 can never fit; sets budget ~90-100. r20's phase-size thesis was
// untested, killed by spills. Salvage: BK=64 at DEPTH-1 (56 set-regs).
// Depth > 1 is worthless anyway: r14 proved every __syncthreads drains vmcnt,
// so r13's "depth-2" never carried loads across a barrier — its 10.4 B/cy/CU
// came from 112KB ISSUED PER PHASE, which depth-1 preserves. r15's regression
// was the 2-barrier single-LDS shape, not single-set: with DOUBLE LDS buffer
// + single reg set the phase is LOADSET(k+1) -> COMPUTE(buf k) -> CVTWRITE
// (-> buf k+1) -> bar: one barrier, loads hidden under COMPUTE, no hazard
// (write targets the non-read buffer; next phase writes the one just read).
//  - r17 balanced split (nrows<=192, 256 blocks, 1/CU) + r19 MT=192 acc diet
//  - A-loads predicated on row < nrows (r20-proven correct): ~0.15MB/block cut
//  - regs: set 56 + acc 96 + addr/scan ~40 = ~190 << 256 (2 waves/SIMD)
// Max-per-CU issued ~1.62MB @ ~10 B/cy ceiling -> ~66us + overheads.
// Canaries: WRITE ~32.7MB (spill), VGPR <= ~210, LDS ~130K.
__global__ __launch_bounds__(512, 2) void gemm_kernel(
    const float* __restrict__ x, const float* __restrict__ W,
    const float* __restrict__ bias, const int* __restrict__ sidx,
    float* __restrict__ out)
{
  __shared__ __align__(16) short lds[2 * (TSZA + TSZB)]; // 129024 B flat
  __shared__ int row_ids[MT];
  __shared__ int wsum[8];
  short* const As0 = lds;
  short* const Bs0 = lds + TSZA;
  short* const As1 = lds + TSZA + TSZB;
  short* const Bs1 = lds + 2 * TSZA + TSZB;

  // ---- XCD-clustered decode ----
  const int hw    = blockIdx.x;          // 0..255, assumed XCD = hw % 8
  const int xcd   = hw & (NXCD - 1);
  const int r     = hw >> 3;             // 0..31: within-XCD sequence
  const int s     = xcd * EPX + (r / BPE);   // expert, clustered per XCD
  const int rr    = r % BPE;             // 0..7
  const int ntile = rr >> 1;             // 0..3 (W slice shared by 2 mtiles)
  const int mtile = rr & 1;
  const int tid   = threadIdx.x;

  const int lane = tid & 63;
  const int wv   = tid >> 6;            // wave id 0..7
  const int wm   = wv >> 2;             // 0..1 : 96-row half
  const int wn   = wv & 3;              // 0..3 : 64-col quarter
  const int fr   = lane & 15;           // fragment row within 16
  const int kg   = lane >> 4;           // fragment k-group (k = kg*8 + j)

  // ---- staging: row = 256 B fp32 = 16 x 16-B chunks; 512 thr -> 32 rows/instr
  const int srw = tid >> 4;             // 0..31 : row within 32-row group
  const int sch = tid & 15;             // 16-B chunk within 256-B k-row

  // B byte-offsets + k0 B-loads issued before the sidx scan.
  unsigned boff[8];
  floatx4 wr[8];
  {
    const unsigned wbyte =
        (unsigned)(((size_t)s * DIM * DIM + (size_t)(ntile * NTILE) * DIM) * 4u);
#pragma unroll
    for (int j = 0; j < 8; ++j) {
      const int tr = j * 32 + srw;
      boff[j] = wbyte + (unsigned)((tr * DIM + sch * 4) * 4);
      wr[j] = *(const floatx4*)((const char*)W + boff[j]);
    }
  }

  // ---- ranked compaction via shfl wave-scan (2 barriers total) ----
  const intx4* sv = (const intx4*)(sidx + tid * 16);
  int c = 0;
#pragma unroll
  for (int j = 0; j < 4; ++j) {
    const intx4 v = sv[j];
#pragma unroll
    for (int e = 0; e < 4; ++e) c += (v[e] == s);
  }
  int ic = c;                           // in-wave inclusive prefix
#pragma unroll
  for (int d = 1; d < 64; d <<= 1) {
    const int t = __shfl_up(ic, d);
    if (lane >= d) ic += t;
  }
  if (lane == 63) wsum[wv] = ic;
  __syncthreads();
  int wbase = 0, total = 0;
#pragma unroll
  for (int w = 0; w < 8; ++w) {
    const int v = wsum[w];
    total += v;
    if (w < wv) wbase += v;
  }
  // balanced split: mtile0 -> ranks [0,h), mtile1 -> [h,total); h=ceil(total/2)
  const int h     = (total + 1) >> 1;    // <= 192 for total <= 384 (validated)
  const int lo    = mtile * h;
  const int hi    = mtile ? total : h;
  const int nrows = hi - lo;
  if (nrows == 0) return;               // uniform across block
  const int base_rank = wbase + ic - c; // exclusive global prefix

  if (tid < MT) row_ids[tid] = -1;
  __syncthreads();
  {
    int r2 = base_rank;
#pragma unroll
    for (int j = 0; j < 4; ++j) {
      const intx4 v = sv[j];
#pragma unroll
      for (int e = 0; e < 4; ++e) {
        if (v[e] == s) {
          if (r2 >= lo && r2 < hi) row_ids[r2 - lo] = tid * 16 + 4 * j + e;
          ++r2;
        }
      }
    }
  }
  __syncthreads();

  // A byte-offsets; loads predicated on row < nrows (r20-proven: garbage
  // regs -> garbage LDS rows -> masked at epilogue; no traps).
  unsigned aoff[6];
  floatx4 xr[6];
#pragma unroll
  for (int j = 0; j < 6; ++j) {
    int ar = row_ids[j * 32 + srw];
    if (ar < 0) ar = 0;
    aoff[j] = (unsigned)((ar * DIM + sch * 4) * 4);
    if (j * 32 + srw < nrows)
      xr[j] = *(const floatx4*)((const char*)x + aoff[j]);   // k0 A
  }

  floatx4 acc[6][4] = {};

#define LOADSET(KB)                                                            \
  {                                                                            \
    _Pragma("unroll")                                                          \
    for (int j = 0; j < 6; ++j)                                                \
      if (j * 32 + srw < nrows)                                                \
        xr[j] = *(const floatx4*)((const char*)x + aoff[j] + (KB) * (BK * 4)); \
    _Pragma("unroll")                                                          \
    for (int j = 0; j < 8; ++j)                                                \
      wr[j] = *(const floatx4*)((const char*)W + boff[j] + (KB) * (BK * 4));   \
  }

#define CVTWRITE(AS, BS)                                                       \
  {                                                                            \
    _Pragma("unroll")                                                          \
    for (int j = 0; j < 6; ++j) {                                              \
      const int off = (j * 32 + srw) * LROW + sch * 4;                         \
      uintx2 ua = { pack_bf16_2(xr[j][0], xr[j][1]),                           \
                    pack_bf16_2(xr[j][2], xr[j][3]) };                         \
      *(uintx2*)&AS[off] = ua;                                                 \
    }                                                                          \
    _Pragma("unroll")                                                          \
    for (int j = 0; j < 8; ++j) {                                              \
      const int off = (j * 32 + srw) * LROW + sch * 4;                         \
      uintx2 ub = { pack_bf16_2(wr[j][0], wr[j][1]),                           \
                    pack_bf16_2(wr[j][2], wr[j][3]) };                         \
      *(uintx2*)&BS[off] = ub;                                                 \
    }                                                                          \
  }

#define COMPUTE(AS, BS)                                                        \
  {                                                                            \
    _Pragma("unroll")                                                          \
    for (int s2 = 0; s2 < 2; ++s2) {                                           \
      short8 fb[4];                                                            \
      _Pragma("unroll")                                                        \
      for (int i = 0; i < 4; ++i)                                              \
        fb[i] = *(const short8*)&BS[(wn * 64 + i * 16 + fr) * LROW + s2 * 32 + kg * 8]; \
      _Pragma("unroll")                                                        \
      for (int mi = 0; mi < 6; ++mi) {                                         \
        const short8 fa = *(const short8*)&AS[(wm * 96 + mi * 16 + fr) * LROW + s2 * 32 + kg * 8]; \
        _Pragma("unroll")                                                      \
        for (int ni = 0; ni < 4; ++ni)                                         \
          acc[mi][ni] = __builtin_amdgcn_mfma_f32_16x16x32_bf16(               \
              fa, fb[ni], acc[mi][ni], 0, 0, 0);                               \
      }                                                                        \
    }                                                                          \
  }

  // prologue: k0 (in regs) -> LDS0
  CVTWRITE(As0, Bs0);
  __syncthreads();

  // depth-1 single-set pair loop, ONE barrier per phase:
  //   phase: LOADSET(k+1) [issue]; COMPUTE(buf k&1) [hide]; CVTWRITE
  //   (-> buf (k+1)&1) [counted-vmcnt wait + pack + write]; barrier.
  // Write targets the buffer NOT being read this phase; next phase writes
  // the buffer just read (after the barrier) — no hazard, r13's phase shape.
  for (int kb = 0; kb < KITERS; kb += 2) {
    LOADSET(kb + 1);                    // kb <= 14 -> kb+1 <= 15 always valid
    COMPUTE(As0, Bs0);
    CVTWRITE(As1, Bs1);
    __syncthreads();

    if (kb + 2 < KITERS) LOADSET(kb + 2);
    COMPUTE(As1, Bs1);
    if (kb + 2 < KITERS) CVTWRITE(As0, Bs0);
    __syncthreads();
  }

#undef LOADSET
#undef CVTWRITE
#undef COMPUTE

  // ---- coalesced epilogue (r12; 192 rows -> up to 6 passes of 32) ---------
  // acc: tile row = wm*96 + mi*16 + kg*4 + q, col = wn*64 + ni*16 + fr.
  // Pass p: rows [32p,32p+32) via [32][260] f32 aliased onto lds (33280 B).
  // One dwordx4 store = 64 lanes x 16 B = FULL 1-KB output row. Early break
  // when the window is beyond nrows (block-uniform).
  float* obuf = (float*)lds;
  const int col0 = ntile * NTILE + wn * 64;
  float bv[4];
#pragma unroll
  for (int ni = 0; ni < 4; ++ni) bv[ni] = bias[s * DIM + col0 + ni * 16 + fr];

  const int rbase = tid >> 6;          // 0..7 : row within 8-row store group
  const int ch    = tid & 63;          // 16-B chunk within 1-KB row

#pragma unroll
  for (int p = 0; p < 6; ++p) {
    if (p * 32 >= nrows) break;        // block-uniform: no divergence
    if (wm == (p >= 3 ? 1 : 0)) {
#pragma unroll
      for (int mh = 0; mh < 2; ++mh) {
        const int mi = (p % 3) * 2 + mh;
        const int lr = mi * 16 + kg * 4 - (p % 3) * 32;   // 0..28 local row base
#pragma unroll
        for (int q = 0; q < 4; ++q)
#pragma unroll
          for (int ni = 0; ni < 4; ++ni)
            obuf[(lr + q) * 260 + wn * 64 + ni * 16 + fr] = acc[mi][ni][q] + bv[ni];
      }
    }
    __syncthreads();
#pragma unroll
    for (int j = 0; j < 4; ++j) {
      const int lr = j * 8 + rbase;              // 0..31
      const int ml = p * 32 + lr;                // tile row
      if (ml < nrows) {
        const int orow = row_ids[ml];
        const floatx4 v = *(const floatx4*)&obuf[lr * 260 + ch * 4];
        *(floatx4*)&out[(size_t)orow * DIM + ntile * NTILE + ch * 4] = v;
      }
    }
    __syncthreads();
  }
}

extern "C" void kernel_launch(void* const* d_in, const int* in_sizes, int n_in,
                              void* d_out, int out_size, void* d_ws, size_t ws_size,
                              hipStream_t stream) {
  const float* x    = (const float*)d_in[0];
  const float* W    = (const float*)d_in[1];
  const float* b    = (const float*)d_in[2];
  const int*   sidx = (const int*)d_in[3];
  float* out = (float*)d_out;
  (void)d_ws; (void)ws_size;  // OFF-LIMITS: any ws touch => 512MiB re-poison
                              // fill (~80us) per iteration (r9 post-mortem)

  hipLaunchKernelGGL(gemm_kernel, dim3(NSESS * TPE * (DIM / NTILE)), dim3(512),
                     0, stream, x, W, b, sidx, out);
}

// Round 17
// 241.421 us; speedup vs baseline: 1.4413x; 1.1635x over previous
//
#include <hip/hip_runtime.h>
#include <cstddef>

#define B_ROWS 8192
#define DIM    1024
#define NSESS  32
#define MT     192       // rows per M-tile; balanced split guarantees nrows<=192
#define NTILE  256       // cols per N-tile
#define BK     32        // fp32 per K-chunk per phase = 1 MFMA k-step
#define KITERS (DIM / BK)   // 32
#define TPE    2         // m-tiles per expert (balanced halves)
#define LROW   40        // shorts per LDS row: 32 bf16 + 8 pad = 80 B (16B-mult)
#define TSZA   (MT * LROW)      // 7680 shorts
#define TSZB   (NTILE * LROW)   // 10240 shorts
#define NXCD   8
#define EPX    (NSESS / NXCD)        // experts per XCD = 4
#define BPE    (TPE * (DIM / NTILE)) // blocks per expert = 8

typedef __attribute__((ext_vector_type(8))) short short8;
typedef __attribute__((ext_vector_type(4))) float floatx4;
typedef __attribute__((ext_vector_type(4))) int intx4;
typedef __attribute__((ext_vector_type(2))) unsigned int uintx2;

// RNE fp32->bf16 for two values, packed into one dword via v_perm_b32.
__device__ __forceinline__ unsigned pack_bf16_2(float fa, float fb) {
  unsigned a = __builtin_bit_cast(unsigned, fa);
  unsigned b = __builtin_bit_cast(unsigned, fb);
  a += 0x7fffu + ((a >> 16) & 1u);
  b += 0x7fffu + ((b >> 16) & 1u);
  return __builtin_amdgcn_perm(b, a, 0x07060302u); // low = bf16(fa), high = bf16(fb)
}

// Round-22 (post-mortem r21: BK=64 single-set STILL spilled — WRITE 46.6MB,
// FETCH +14MB, 119us; third BK=64@512thr register death (r11/r20/r21).
// BK=64 closed: held = 3.5xBK xdepth + frags + addr never fits under acc>=96.
// Clean frontier = r19 (91.5us, BK=32 depth-3 MT=192 balanced, WRITE exactly
// 32.7MB). Accounting: issued/block = B 1.0MB + A 0.77MB (all 192 rows incl.
// 40-90 DUMMY row-0 re-loads; typical nrows 105-155) = 1.77MB -> 69us at the
// 10.2 B/cy/CU m13 ceiling + ~20us overhead. This round = r19 + A-load
// predication ONLY (r20/r21 proved the pattern correct; their failures were
// spill, and r19 has slack: 116 arch + 96 acc = 212/256):
//  - guard prologue + LOADSET A-loads with (row < nrows); dummy rows carry
//    garbage regs -> garbage LDS rows -> masked at epilogue (no traps).
//  - max-per-CU issued 1.77 -> ~1.55-1.6MB.
// Canaries: WRITE must stay 32.7MB + VGPR <= ~125, else predication itself
// is implicated and gets reverted. If gain <5% clean: declare roofline
// (65us compulsory service + ~25us structural overhead).
__global__ __launch_bounds__(512, 2) void gemm_kernel(
    const float* __restrict__ x, const float* __restrict__ W,
    const float* __restrict__ bias, const int* __restrict__ sidx,
    float* __restrict__ out)
{
  __shared__ __align__(16) short lds[2 * TSZA + 2 * TSZB]; // 71680 B flat
  __shared__ int row_ids[MT];
  __shared__ int wsum[8];
  short* const As0 = lds;
  short* const As1 = lds + TSZA;
  short* const Bs0 = lds + 2 * TSZA;
  short* const Bs1 = lds + 2 * TSZA + TSZB;

  // ---- XCD-clustered decode ----
  const int hw    = blockIdx.x;          // 0..255, assumed XCD = hw % 8
  const int xcd   = hw & (NXCD - 1);
  const int r     = hw >> 3;             // 0..31: within-XCD sequence
  const int s     = xcd * EPX + (r / BPE);   // expert, clustered per XCD
  const int rr    = r % BPE;             // 0..7
  const int ntile = rr >> 1;             // 0..3 (W slice shared by 2 mtiles)
  const int mtile = rr & 1;
  const int tid   = threadIdx.x;

  const int lane = tid & 63;
  const int wv   = tid >> 6;            // wave id 0..7
  const int wm   = wv >> 2;             // 0..1 : 96-row half
  const int wn   = wv & 3;              // 0..3 : 64-col quarter
  const int fr   = lane & 15;           // fragment row within 16
  const int kg   = lane >> 4;           // fragment k-group (k = kg*8 + j)

  // ---- staging: row = 128 B fp32 = 8 x 16-B chunks; 512 thr -> 64 rows/instr
  const int srw = tid >> 3;             // 0..63 : row within 64-row group
  const int sch = tid & 7;              // 16-B chunk within 128-B k-row

  // B byte-offsets + chunk 0/1/2 B-loads issued before the sidx scan.
  unsigned boff[4];
  floatx4 wr0[4], wr1[4], wr2[4];
  {
    const unsigned wbyte =
        (unsigned)(((size_t)s * DIM * DIM + (size_t)(ntile * NTILE) * DIM) * 4u);
#pragma unroll
    for (int j = 0; j < 4; ++j) {
      const int tr = j * 64 + srw;
      boff[j] = wbyte + (unsigned)((tr * DIM + sch * 4) * 4);
      wr0[j] = *(const floatx4*)((const char*)W + boff[j]);
    }
#pragma unroll
    for (int j = 0; j < 4; ++j)
      wr1[j] = *(const floatx4*)((const char*)W + boff[j] + (BK * 4));
#pragma unroll
    for (int j = 0; j < 4; ++j)
      wr2[j] = *(const floatx4*)((const char*)W + boff[j] + 2 * (BK * 4));
  }

  // ---- ranked compaction via shfl wave-scan (2 barriers total) ----
  const intx4* sv = (const intx4*)(sidx + tid * 16);
  int c = 0;
#pragma unroll
  for (int j = 0; j < 4; ++j) {
    const intx4 v = sv[j];
#pragma unroll
    for (int e = 0; e < 4; ++e) c += (v[e] == s);
  }
  int ic = c;                           // in-wave inclusive prefix
#pragma unroll
  for (int d = 1; d < 64; d <<= 1) {
    const int t = __shfl_up(ic, d);
    if (lane >= d) ic += t;
  }
  if (lane == 63) wsum[wv] = ic;
  __syncthreads();
  int wbase = 0, total = 0;
#pragma unroll
  for (int w = 0; w < 8; ++w) {
    const int v = wsum[w];
    total += v;
    if (w < wv) wbase += v;
  }
  // balanced split: mtile0 -> ranks [0,h), mtile1 -> [h,total); h=ceil(total/2)
  const int h     = (total + 1) >> 1;    // <= 192 for total <= 384 (validated)
  const int lo    = mtile * h;
  const int hi    = mtile ? total : h;
  const int nrows = hi - lo;
  if (nrows == 0) return;               // uniform across block
  const int base_rank = wbase + ic - c; // exclusive global prefix

  if (tid < MT) row_ids[tid] = -1;
  __syncthreads();
  {
    int r2 = base_rank;
#pragma unroll
    for (int j = 0; j < 4; ++j) {
      const intx4 v = sv[j];
#pragma unroll
      for (int e = 0; e < 4; ++e) {
        if (v[e] == s) {
          if (r2 >= lo && r2 < hi) row_ids[r2 - lo] = tid * 16 + 4 * j + e;
          ++r2;
        }
      }
    }
  }
  __syncthreads();

  // A offsets; loads predicated on row < nrows (r20/r21-proven correct:
  // garbage regs -> garbage LDS rows -> masked at epilogue; no traps).
  unsigned aoff[3];
  floatx4 xr0[3], xr1[3], xr2[3];
#pragma unroll
  for (int j = 0; j < 3; ++j) {
    int ar = row_ids[j * 64 + srw];
    if (ar < 0) ar = 0;
    aoff[j] = (unsigned)((ar * DIM + sch * 4) * 4);
    if (j * 64 + srw < nrows)
      xr0[j] = *(const floatx4*)((const char*)x + aoff[j]);                 // k0
  }
#pragma unroll
  for (int j = 0; j < 3; ++j)
    if (j * 64 + srw < nrows)
      xr1[j] = *(const floatx4*)((const char*)x + aoff[j] + (BK * 4));      // k1
#pragma unroll
  for (int j = 0; j < 3; ++j)
    if (j * 64 + srw < nrows)
      xr2[j] = *(const floatx4*)((const char*)x + aoff[j] + 2 * (BK * 4));  // k2

  floatx4 acc[6][4] = {};

#define LOADSET(XR, WR, KB)                                                    \
  {                                                                            \
    _Pragma("unroll")                                                          \
    for (int j = 0; j < 3; ++j)                                                \
      if (j * 64 + srw < nrows)                                                \
        XR[j] = *(const floatx4*)((const char*)x + aoff[j] + (KB) * (BK * 4)); \
    _Pragma("unroll")                                                          \
    for (int j = 0; j < 4; ++j)                                                \
      WR[j] = *(const floatx4*)((const char*)W + boff[j] + (KB) * (BK * 4));   \
  }

#define CVTWRITE(XR, WR, AS, BS)                                               \
  {                                                                            \
    _Pragma("unroll")                                                          \
    for (int j = 0; j < 3; ++j) {                                              \
      const int off = (j * 64 + srw) * LROW + sch * 4;                         \
      uintx2 ua = { pack_bf16_2(XR[j][0], XR[j][1]),                           \
                    pack_bf16_2(XR[j][2], XR[j][3]) };                         \
      *(uintx2*)&AS[off] = ua;                                                 \
    }                                                                          \
    _Pragma("unroll")                                                          \
    for (int j = 0; j < 4; ++j) {                                              \
      const int off = (j * 64 + srw) * LROW + sch * 4;                         \
      uintx2 ub = { pack_bf16_2(WR[j][0], WR[j][1]),                           \
                    pack_bf16_2(WR[j][2], WR[j][3]) };                         \
      *(uintx2*)&BS[off] = ub;                                                 \
    }                                                                          \
  }

#define COMPUTE(AS, BS)                                                        \
  {                                                                            \
    short8 fb[4];                                                              \
    _Pragma("unroll")                                                          \
    for (int i = 0; i < 4; ++i)                                                \
      fb[i] = *(const short8*)&BS[(wn * 64 + i * 16 + fr) * LROW + kg * 8];    \
    _Pragma("unroll")                                                          \
    for (int mi = 0; mi < 6; ++mi) {                                           \
      const short8 fa = *(const short8*)&AS[(wm * 96 + mi * 16 + fr) * LROW + kg * 8]; \
      _Pragma("unroll")                                                        \
      for (int ni = 0; ni < 4; ++ni)                                           \
        acc[mi][ni] = __builtin_amdgcn_mfma_f32_16x16x32_bf16(                 \
            fa, fb[ni], acc[mi][ni], 0, 0, 0);                                 \
    }                                                                          \
  }

  // phase K: compute chunk K from LDS[K&1]; stage set (K+1)%3 (chunk K+1)
  // into LDS[(K+1)&1]; refill that set with chunk K+4; barrier. Static
  // indices via period-6 expansion.
#define PHASE(K, CUR, NXT, XR, WR)                                             \
  {                                                                            \
    COMPUTE(As##CUR, Bs##CUR);                                                 \
    if ((K) + 1 < KITERS) CVTWRITE(XR, WR, As##NXT, Bs##NXT);                  \
    if ((K) + 4 < KITERS) LOADSET(XR, WR, (K) + 4);                            \
    __syncthreads();                                                           \
  }

  // prologue: chunk 0 (set0) -> LDS0; REFILL set0 with chunk 3 (r19 fix —
  // PHASE(2) stages chunk 3 from set0). Sets hold {3,1,2} entering the loop.
  CVTWRITE(xr0, wr0, As0, Bs0);
  LOADSET(xr0, wr0, 3);
  __syncthreads();

  PHASE( 0, 0, 1, xr1, wr1)  PHASE( 1, 1, 0, xr2, wr2)  PHASE( 2, 0, 1, xr0, wr0)
  PHASE( 3, 1, 0, xr1, wr1)  PHASE( 4, 0, 1, xr2, wr2)  PHASE( 5, 1, 0, xr0, wr0)
  PHASE( 6, 0, 1, xr1, wr1)  PHASE( 7, 1, 0, xr2, wr2)  PHASE( 8, 0, 1, xr0, wr0)
  PHASE( 9, 1, 0, xr1, wr1)  PHASE(10, 0, 1, xr2, wr2)  PHASE(11, 1, 0, xr0, wr0)
  PHASE(12, 0, 1, xr1, wr1)  PHASE(13, 1, 0, xr2, wr2)  PHASE(14, 0, 1, xr0, wr0)
  PHASE(15, 1, 0, xr1, wr1)  PHASE(16, 0, 1, xr2, wr2)  PHASE(17, 1, 0, xr0, wr0)
  PHASE(18, 0, 1, xr1, wr1)  PHASE(19, 1, 0, xr2, wr2)  PHASE(20, 0, 1, xr0, wr0)
  PHASE(21, 1, 0, xr1, wr1)  PHASE(22, 0, 1, xr2, wr2)  PHASE(23, 1, 0, xr0, wr0)
  PHASE(24, 0, 1, xr1, wr1)  PHASE(25, 1, 0, xr2, wr2)  PHASE(26, 0, 1, xr0, wr0)
  PHASE(27, 1, 0, xr1, wr1)  PHASE(28, 0, 1, xr2, wr2)  PHASE(29, 1, 0, xr0, wr0)
  PHASE(30, 0, 1, xr1, wr1)  PHASE(31, 1, 0, xr2, wr2)

#undef PHASE
#undef LOADSET
#undef CVTWRITE
#undef COMPUTE

  // ---- coalesced epilogue (r12; 192 rows -> up to 6 passes of 32) ---------
  // acc: tile row = wm*96 + mi*16 + kg*4 + q, col = wn*64 + ni*16 + fr.
  // Pass p: rows [32p,32p+32) via [32][260] f32 aliased onto lds (33280 B).
  // One dwordx4 store = 64 lanes x 16 B = FULL 1-KB output row. Early break
  // when the window is beyond nrows (block-uniform).
  float* obuf = (float*)lds;
  const int col0 = ntile * NTILE + wn * 64;
  float bv[4];
#pragma unroll
  for (int ni = 0; ni < 4; ++ni) bv[ni] = bias[s * DIM + col0 + ni * 16 + fr];

  const int rbase = tid >> 6;          // 0..7 : row within 8-row store group
  const int ch    = tid & 63;          // 16-B chunk within 1-KB row

#pragma unroll
  for (int p = 0; p < 6; ++p) {
    if (p * 32 >= nrows) break;        // block-uniform: no divergence
    if (wm == (p >= 3 ? 1 : 0)) {
#pragma unroll
      for (int mh = 0; mh < 2; ++mh) {
        const int mi = (p % 3) * 2 + mh;
        const int lr = mi * 16 + kg * 4 - (p % 3) * 32;   // 0..28 local row base
#pragma unroll
        for (int q = 0; q < 4; ++q)
#pragma unroll
          for (int ni = 0; ni < 4; ++ni)
            obuf[(lr + q) * 260 + wn * 64 + ni * 16 + fr] = acc[mi][ni][q] + bv[ni];
      }
    }
    __syncthreads();
#pragma unroll
    for (int j = 0; j < 4; ++j) {
      const int lr = j * 8 + rbase;              // 0..31
      const int ml = p * 32 + lr;                // tile row
      if (ml < nrows) {
        const int orow = row_ids[ml];
        const floatx4 v = *(const floatx4*)&obuf[lr * 260 + ch * 4];
        *(floatx4*)&out[(size_t)orow * DIM + ntile * NTILE + ch * 4] = v;
      }
    }
    __syncthreads();
  }
}

extern "C" void kernel_launch(void* const* d_in, const int* in_sizes, int n_in,
                              void* d_out, int out_size, void* d_ws, size_t ws_size,
                              hipStream_t stream) {
  const float* x    = (const float*)d_in[0];
  const float* W    = (const float*)d_in[1];
  const float* b    = (const float*)d_in[2];
  const int*   sidx = (const int*)d_in[3];
  float* out = (float*)d_out;
  (void)d_ws; (void)ws_size;  // OFF-LIMITS: any ws touch => 512MiB re-poison
                              // fill (~80us) per iteration (r9 post-mortem)

  hipLaunchKernelGGL(gemm_kernel, dim3(NSESS * TPE * (DIM / NTILE)), dim3(512),
                     0, stream, x, W, b, sidx, out);
}